// Round 16
// baseline (109.061 us; speedup 1.0000x reference)
//
#include <hip/hip_runtime.h>
#include <hip/hip_bf16.h>
#include <math.h>

// Problem constants
constexpr int B_  = 16;
constexpr int C_  = 512;
constexpr int N_  = 1024;   // 32*32 tokens
constexpr int NH_ = 8;
constexpr int HD_ = 64;

// 1/sqrt(64) * log2(e): softmax computed in exp2 domain
#define QSCALE 0.18033688f

typedef __attribute__((ext_vector_type(8))) short short8;
typedef __attribute__((ext_vector_type(4))) short short4v;
typedef __attribute__((ext_vector_type(4))) float f32x4;
#define MFMA16(a, b, c) __builtin_amdgcn_mfma_f32_16x16x32_bf16((a), (b), (c), 0, 0, 0)

#if __has_builtin(__builtin_amdgcn_exp2f)
#define EXP2(x) __builtin_amdgcn_exp2f(x)
#else
#define EXP2(x) exp2f(x)
#endif

__device__ __forceinline__ short f2bf(float f) {          // manual RNE (prep kernels)
    union { float f; unsigned u; } a; a.f = f;
    unsigned r = a.u + 0x7fffu + ((a.u >> 16) & 1u);
    return (short)(r >> 16);
}
__device__ __forceinline__ short f2bf_hw(float f) {       // hardware cvt (hot paths)
    __hip_bfloat16 h = __float2bfloat16(f);
    return *reinterpret_cast<short*>(&h);
}

// async global->LDS, 16B per lane; LDS dest = wave-uniform base + lane*16
__device__ __forceinline__ void gload_lds16(const void* g, void* l) {
    __builtin_amdgcn_global_load_lds(
        (const __attribute__((address_space(1))) unsigned*)g,
        (__attribute__((address_space(3))) unsigned*)l, 16, 0, 0);
}

// ---------------------------------------------------------------------------
// prep_all v2: vectorized transpose+cast (float4 loads, short8 stores).
//   wgid < 2048 : x[b][c][n] f32 -> xt[b][n][c] bf16 (64x64 tiles via LDS)
//   wgid >= 2048: W[c][co] f32 -> WT[co][c] bf16, 4 matrices
// ---------------------------------------------------------------------------
__global__ __launch_bounds__(256) void prep_all(
    const float* __restrict__ x, short* __restrict__ xt,
    const float* __restrict__ Wq, const float* __restrict__ Wk,
    const float* __restrict__ Wv, const float* __restrict__ Wo,
    short* __restrict__ WqT, short* __restrict__ WkT,
    short* __restrict__ WvT, short* __restrict__ WoT) {
    __shared__ float t[64][65];
    const int tid = threadIdx.x;
    const int wgid = blockIdx.x;

    const float* src;  short* dst;
    size_t srow0, scol0, drow0, dcol0;
    if (wgid < 2048) {
        const int xcd = wgid & 7;
        const int i = wgid >> 3;                 // 0..255
        const int b  = 2 * xcd + (i >= 128);
        const int tile = i & 127;
        const int tn = tile >> 3;
        const int tc = tile & 7;
        src = x;  dst = xt;
        srow0 = (size_t)b * C_ + tc * 64;  scol0 = (size_t)tn * 64;
        drow0 = (size_t)b * N_ + tn * 64;  dcol0 = (size_t)tc * 64;
        #pragma unroll
        for (int k = 0; k < 4; ++k) {
            int s = k * 256 + tid;
            int r = s >> 4, c4 = s & 15;
            float4 v = *(const float4*)&src[(srow0 + r) * N_ + scol0 + c4 * 4];
            *(float4*)&t[r][c4 * 4] = v;
        }
        __syncthreads();
        #pragma unroll
        for (int k = 0; k < 2; ++k) {
            int s = k * 256 + tid;
            int r2 = s >> 3, c8 = s & 7;
            short8 pk;
            #pragma unroll
            for (int j = 0; j < 8; ++j) pk[j] = f2bf(t[c8 * 8 + j][r2]);
            *(short8*)&dst[(drow0 + r2) * C_ + dcol0 + c8 * 8] = pk;
        }
    } else {
        const int idx0 = wgid - 2048;            // 0..255
        const int z = idx0 >> 6;
        src = (z == 0) ? Wq : (z == 1) ? Wk : (z == 2) ? Wv : Wo;
        dst = (z == 0) ? WqT : (z == 1) ? WkT : (z == 2) ? WvT : WoT;
        const int tile = idx0 & 63;
        const int tco = tile >> 3;
        const int tc  = tile & 7;
        srow0 = (size_t)tc * 64;   scol0 = (size_t)tco * 64;
        drow0 = (size_t)tco * 64;  dcol0 = (size_t)tc * 64;
        #pragma unroll
        for (int k = 0; k < 4; ++k) {
            int s = k * 256 + tid;
            int r = s >> 4, c4 = s & 15;
            float4 v = *(const float4*)&src[(srow0 + r) * C_ + scol0 + c4 * 4];
            *(float4*)&t[r][c4 * 4] = v;
        }
        __syncthreads();
        #pragma unroll
        for (int k = 0; k < 2; ++k) {
            int s = k * 256 + tid;
            int r2 = s >> 3, c8 = s & 7;
            short8 pk;
            #pragma unroll
            for (int j = 0; j < 8; ++j) pk[j] = f2bf(t[c8 * 8 + j][r2]);
            *(short8*)&dst[(drow0 + r2) * C_ + dcol0 + c8 * 8] = pk;
        }
    }
}

// ===========================================================================
// m97-style GEMM core macros (shared by qkv_mfma and proj_mfma):
// 128x128 tile, BK=64, 2x2 waves of 64x64. Double-buffered LDS staged via
// global_load_lds width=16, pre-swizzled global source (slot ^ (row&7)) with
// linear LDS dest; ds_read applies the same XOR -> conflict-free b128.
// smem layout: short smem[2][2][128][64] = 64 KB.
// ===========================================================================
#define GEMM_STAGE(buf, t)                                                    \
    {                                                                         \
        _Pragma("unroll")                                                     \
        for (int ii = 0; ii < 4; ++ii) {                                      \
            gload_lds16(Ag + arowoff + (size_t)ii * 8 * C_ + (t) * 64,        \
                        &smem[buf][0][wave * 32 + ii * 8][0]);                \
            gload_lds16(Bg + arowoff + (size_t)ii * 8 * C_ + (t) * 64,        \
                        &smem[buf][1][wave * 32 + ii * 8][0]);                \
        }                                                                     \
    }

#define GEMM_CORE()                                                           \
    GEMM_STAGE(0, 0);                                                         \
    __syncthreads();                                                          \
    for (int t = 0; t < 8; ++t) {                                             \
        const int buf = t & 1;                                                \
        if (t < 7) GEMM_STAGE(buf ^ 1, t + 1);                                \
        __builtin_amdgcn_s_setprio(1);                                        \
        _Pragma("unroll")                                                     \
        for (int ks = 0; ks < 2; ++ks) {                                      \
            short8 af[4], bf[4];                                              \
            const int sw = ((ks * 4 + g) ^ (c & 7)) << 3;                     \
            _Pragma("unroll")                                                 \
            for (int fm = 0; fm < 4; ++fm)                                    \
                af[fm] = *(const short8*)&smem[buf][0][wm * 64 + fm * 16 + c][sw]; \
            _Pragma("unroll")                                                 \
            for (int fn = 0; fn < 4; ++fn)                                    \
                bf[fn] = *(const short8*)&smem[buf][1][wn * 64 + fn * 16 + c][sw]; \
            _Pragma("unroll")                                                 \
            for (int fm = 0; fm < 4; ++fm)                                    \
                _Pragma("unroll")                                             \
                for (int fn = 0; fn < 4; ++fn)                                \
                    acc[fm][fn] = MFMA16(af[fm], bf[fn], acc[fm][fn]);        \
        }                                                                     \
        __builtin_amdgcn_s_setprio(0);                                        \
        __syncthreads();                                                      \
    }

// ---------------------------------------------------------------------------
// qkv_mfma: Y = xf @ W + b. 1D grid 1536, XCD-consistent swizzle.
// z=0 -> Qs (scaled), z=1 -> Kb, both [b,h,tok,hd]; z=2 -> Vt [b,h,hd,key].
// ---------------------------------------------------------------------------
__global__ __launch_bounds__(256) void qkv_mfma(
    const short* __restrict__ xt,
    const short* __restrict__ WqT, const float* __restrict__ bq,
    const short* __restrict__ WkT, const float* __restrict__ bk,
    const short* __restrict__ WvT, const float* __restrict__ bv,
    short* __restrict__ Qs, short* __restrict__ Kb, short* __restrict__ Vt) {
    const int wgid = blockIdx.x;
    const int xcd = wgid & 7;
    const int i = wgid >> 3;                 // 0..191
    const int b = 2 * xcd + (i >= 96);
    const int rem = (i >= 96) ? i - 96 : i;  // 0..95
    const int z = rem >> 5;                  // 0..2
    const int tile = rem & 31;
    const int mt = tile >> 2;                // 0..7 token tile (128 wide)
    const int nt = tile & 3;                 // 0..3 cout tile (128 wide)
    const int tid = threadIdx.x;
    const int wave = tid >> 6, lane = tid & 63;
    const int g = lane >> 4, c = lane & 15;
    const int wm = wave >> 1, wn = wave & 1;

    const short* W    = (z == 0) ? WqT : (z == 1) ? WkT : WvT;
    const float* bias = (z == 0) ? bq  : (z == 1) ? bk  : bv;

    __shared__ __align__(16) short smem[2][2][128][64];

    const short* Ag = xt + (size_t)b * N_ * C_ + (size_t)mt * 128 * C_;
    const short* Bg = W + (size_t)nt * 128 * C_;

    const int lrow = lane >> 3, lslot = lane & 7;
    const size_t arowoff = (size_t)(wave * 32 + lrow) * C_ + ((lslot ^ lrow) << 3);

    f32x4 acc[4][4] = {};
    GEMM_CORE();

    const int tok0 = mt * 128 + wm * 64;
    const int co0  = nt * 128 + wn * 64;
    const int h = co0 >> 6;
    const size_t bh = (size_t)(b * NH_ + h);

    if (z < 2) {
        short* Y = (z == 0) ? Qs : Kb;
        const float sc = (z == 0) ? QSCALE : 1.f;
        #pragma unroll
        for (int fm = 0; fm < 4; ++fm)
            #pragma unroll
            for (int fn = 0; fn < 4; ++fn)
                #pragma unroll
                for (int r = 0; r < 4; ++r) {
                    int tok = tok0 + fm * 16 + 4 * g + r;
                    int hd  = fn * 16 + c;
                    float v = (acc[fm][fn][r] + bias[co0 + hd]) * sc;
                    Y[(bh * N_ + tok) * HD_ + hd] = f2bf_hw(v);
                }
    } else {
        // V transpose via per-wave LDS (aliases staging smem after final barrier)
        short (*t72)[72] = (short(*)[72])((short*)smem + wave * 32 * 72);
        #pragma unroll
        for (int p = 0; p < 2; ++p) {       // two 32-row passes (in-order DS per wave)
            #pragma unroll
            for (int fn2 = 0; fn2 < 2; ++fn2) {
                int fnn = 2 * p + fn2;
                #pragma unroll
                for (int fm = 0; fm < 4; ++fm) {
                    short4v pk;
                    #pragma unroll
                    for (int r = 0; r < 4; ++r)
                        pk[r] = f2bf_hw(acc[fm][fnn][r] + bias[co0 + fnn * 16 + c]);
                    *(short4v*)&t72[fn2 * 16 + c][fm * 16 + 4 * g] = pk;
                }
            }
            int row = lane >> 1, half2 = lane & 1;
            int hd = p * 32 + row;
            size_t base = (bh * HD_ + hd) * N_ + tok0 + half2 * 32;
            #pragma unroll
            for (int j = 0; j < 4; ++j)
                *(short8*)&Vt[base + j * 8] = *(const short8*)&t72[row][half2 * 32 + j * 8];
        }
    }
}

// ---------------------------------------------------------------------------
// attn_mfma: static-max softmax flash attention, R10/R12 structure, with
// K/V staging via global_load_lds (no register round-trip, no ds_writes):
// each wave stages its 8 K-rows and 8 V-rows; per-lane SOURCE slot is
// inverse-swizzled ((l&7)^((l>>3)&7)) so the linear LDS dest reproduces the
// swizzled layout LDS[row][s] = global[row][s^(row&7)] (rule #21).
// ---------------------------------------------------------------------------
__global__ __launch_bounds__(512) void attn_mfma(
    const short* __restrict__ Qs, const short* __restrict__ Kb,
    const short* __restrict__ Vt, short* __restrict__ Ah) {
    const int wgid = blockIdx.x;
    const int swz  = (wgid & 7) * 64 + (wgid >> 3);    // 512 wgs, bijective
    const int b  = swz >> 5;                           // XCD x owns b={2x,2x+1}
    const int h  = (swz >> 2) & 7;
    const int qt = swz & 3;
    const int tid = threadIdx.x;
    const int wave = tid >> 6, lane = tid & 63;
    const int g = lane >> 4, c = lane & 15;
    const int q0 = qt * 256 + wave * 32;               // wave's 32 q rows
    const size_t bh = (size_t)(b * NH_ + h);

    const short* Qw  = Qs + (bh * N_ + q0) * HD_;
    const short* Kbb = Kb + bh * N_ * HD_;
    const short* Vtb = Vt + bh * HD_ * N_;

    __shared__ __align__(16) short KV[2][2][4096];  // [dbuf][K|V][64x64, swizzled]
    __shared__ short Pl[8][32][64];      // per-wave P, 8B-slot xor-swizzled
    short (*P)[64] = Pl[wave];
    const int px = (c & 7) << 1;         // P-swizzle term (row & 7 == c & 7)

    // gload_lds staging: wave stages rows 8*wave..8*wave+7 of K and of V.
    // lane l -> row rowbase + (l>>3), source slot (l&7)^((l>>3)&7).
    const int rowbase = wave * 8;
    const int srow = lane >> 3;                      // 0..7
    const int sslot = (lane & 7) ^ srow;             // inverse swizzle
    #define STAGE(buf, key0)                                                   \
        do {                                                                   \
            gload_lds16(&Kbb[(size_t)((key0) + rowbase + srow) * HD_ + sslot * 8], \
                        &KV[buf][0][rowbase * 64]);                            \
            gload_lds16(&Vtb[(size_t)(rowbase + srow) * N_ + (key0) + sslot * 8],  \
                        &KV[buf][1][rowbase * 64]);                            \
        } while (0)

    short8 qf[2][2];
    #pragma unroll
    for (int f = 0; f < 2; ++f)
        #pragma unroll
        for (int k0 = 0; k0 < 2; ++k0)
            qf[f][k0] = *(const short8*)&Qw[(f * 16 + c) * HD_ + k0 * 32 + g * 8];

    // ones B-fragment (bf16 1.0) for the l-accumulating MFMA
    short8 ones8;
    #pragma unroll
    for (int j = 0; j < 8; ++j) ones8[j] = (short)0x3F80;

    f32x4 o[2][4] = {};
    f32x4 lacc[2] = {};                  // D[row=q][col] all-equal l partials

    STAGE(0, 0);
    __syncthreads();                     // drains vmcnt -> chunk 0 resident

    int cur = 0;
    for (int it = 0; it < 16; ++it) {
        if (it < 15) STAGE(cur ^ 1, (it + 1) * 64);   // lands during compute

        const short* Kl = &KV[cur][0][0];
        const short* Vl = &KV[cur][1][0];

        f32x4 s[2][4] = {};
        __builtin_amdgcn_s_setprio(1);
        #pragma unroll
        for (int m = 0; m < 4; ++m) {
            const int row = m * 16 + c;
            short8 ka = *(const short8*)&Kl[row * 64 + 8 * ((g)     ^ (row & 7))];
            short8 kb = *(const short8*)&Kl[row * 64 + 8 * ((4 + g) ^ (row & 7))];
            s[0][m] = MFMA16(ka, qf[0][0], s[0][m]);
            s[0][m] = MFMA16(kb, qf[0][1], s[0][m]);
            s[1][m] = MFMA16(ka, qf[1][0], s[1][m]);
            s[1][m] = MFMA16(kb, qf[1][1], s[1][m]);
        }
        __builtin_amdgcn_s_setprio(0);

        // static-max softmax: p = exp2(s); pack to swizzled P (no reductions)
        #pragma unroll
        for (int f = 0; f < 2; ++f) {
            #pragma unroll
            for (int m = 0; m < 4; ++m) {
                short4v pk;
                #pragma unroll
                for (int r = 0; r < 4; ++r) pk[r] = f2bf_hw(EXP2(s[f][m][r]));
                *(short4v*)&P[f * 16 + c][((4 * m + g) ^ px) * 4] = pk;
            }
        }

        short8 pa[2][2];
        #pragma unroll
        for (int f = 0; f < 2; ++f)
            #pragma unroll
            for (int k0 = 0; k0 < 2; ++k0)
                pa[f][k0] = *(const short8*)&P[f * 16 + c][((k0 * 8 + 2 * g) ^ px) * 4];
        __builtin_amdgcn_s_setprio(1);
        // l partials on the matrix pipe: D[q][*] += sum_k P[q][k]
        lacc[0] = MFMA16(pa[0][0], ones8, lacc[0]);
        lacc[0] = MFMA16(pa[0][1], ones8, lacc[0]);
        lacc[1] = MFMA16(pa[1][0], ones8, lacc[1]);
        lacc[1] = MFMA16(pa[1][1], ones8, lacc[1]);
        #pragma unroll
        for (int n = 0; n < 4; ++n) {
            const int row = n * 16 + c;
            short8 va = *(const short8*)&Vl[row * 64 + 8 * ((g)     ^ (row & 7))];
            short8 vb = *(const short8*)&Vl[row * 64 + 8 * ((4 + g) ^ (row & 7))];
            o[0][n] = MFMA16(pa[0][0], va, o[0][n]);
            o[0][n] = MFMA16(pa[0][1], vb, o[0][n]);
            o[1][n] = MFMA16(pa[1][0], va, o[1][n]);
            o[1][n] = MFMA16(pa[1][1], vb, o[1][n]);
        }
        __builtin_amdgcn_s_setprio(0);

        __syncthreads();                 // drains prefetch + all waves done
        cur ^= 1;
    }
    #undef STAGE

    // epilogue: l is lane-local (lacc[f][r] = l of q-row 4g+r); divide, store
    #pragma unroll
    for (int f = 0; f < 2; ++f) {
        float li[4];
        #pragma unroll
        for (int r = 0; r < 4; ++r) li[r] = 1.f / lacc[f][r];
        #pragma unroll
        for (int n = 0; n < 4; ++n)
            #pragma unroll
            for (int r = 0; r < 4; ++r) {
                int tok = q0 + f * 16 + 4 * g + r;
                int cc  = h * 64 + n * 16 + c;
                Ah[((size_t)b * N_ + tok) * C_ + cc] = f2bf_hw(o[f][n][r] * li[r]);
            }
    }
}

// ---------------------------------------------------------------------------
// proj_mfma: out[b,co,n] = bo[co] + sum_k A[tok][k] Wo[k][co]. m97-style
// staged GEMM core, 128x128 tile. 1D grid 512, XCD-consistent swizzle.
// Epilogue transposes 64x64 wave tile via LDS -> coalesced f32 stores.
// ---------------------------------------------------------------------------
__global__ __launch_bounds__(256) void proj_mfma(
    const short* __restrict__ Ah, const short* __restrict__ WoT,
    const float* __restrict__ bo, float* __restrict__ out) {
    const int wgid = blockIdx.x;
    const int xcd = wgid & 7;
    const int i = wgid >> 3;                 // 0..63
    const int b = 2 * xcd + (i >= 32);
    const int tile = i & 31;
    const int mt = tile >> 2;                // 0..7
    const int nt = tile & 3;                 // 0..3
    const int tid = threadIdx.x;
    const int wave = tid >> 6, lane = tid & 63;
    const int g = lane >> 4, c = lane & 15;
    const int wm = wave >> 1, wn = wave & 1;

    __shared__ __align__(16) short smem[2][2][128][64];

    const short* Ag = Ah + (size_t)b * N_ * C_ + (size_t)mt * 128 * C_;
    const short* Bg = WoT + (size_t)nt * 128 * C_;

    const int lrow = lane >> 3, lslot = lane & 7;
    const size_t arowoff = (size_t)(wave * 32 + lrow) * C_ + ((lslot ^ lrow) << 3);

    f32x4 acc[4][4] = {};
    GEMM_CORE();

    const int tok0 = mt * 128 + wm * 64;
    const int co0  = nt * 128 + wn * 64;

    // transpose 64x64 wave tile via LDS (aliases staging smem), two passes
    float (*tf)[68] = (float(*)[68])((float*)smem + wave * 32 * 68);
    #pragma unroll
    for (int p = 0; p < 2; ++p) {
        #pragma unroll
        for (int fm = 0; fm < 4; ++fm)
            #pragma unroll
            for (int fn2 = 0; fn2 < 2; ++fn2) {
                float4 v = *(float4*)&acc[fm][2 * p + fn2];
                *(float4*)&tf[fn2 * 16 + c][fm * 16 + 4 * g] = v;
            }
        int row = lane >> 1, half = lane & 1;
        int co = co0 + p * 32 + row;
        float bias = bo[co];
        float* ob = out + ((size_t)b * C_ + co) * N_ + tok0 + half * 32;
        #pragma unroll
        for (int j = 0; j < 8; ++j) {
            float4 v = *(const float4*)&tf[row][half * 32 + j * 4];
            v.x += bias; v.y += bias; v.z += bias; v.w += bias;
            *(float4*)&ob[j * 4] = v;
        }
    }
}

// ---------------------------------------------------------------------------
extern "C" void kernel_launch(void* const* d_in, const int* in_sizes, int n_in,
                              void* d_out, int out_size, void* d_ws, size_t ws_size,
                              hipStream_t stream) {
    (void)in_sizes; (void)n_in; (void)out_size; (void)ws_size;
    const float* x  = (const float*)d_in[0];
    const float* Wq = (const float*)d_in[1];
    const float* bq = (const float*)d_in[2];
    const float* Wk = (const float*)d_in[3];
    const float* bk = (const float*)d_in[4];
    const float* Wv = (const float*)d_in[5];
    const float* bv = (const float*)d_in[6];
    const float* Wo = (const float*)d_in[7];
    const float* bo = (const float*)d_in[8];
    float* out = (float*)d_out;

    char* ws = (char*)d_ws;
    const size_t MB = 1024 * 1024;
    short* xt  = (short*)(ws + 0 * MB);      // 16 MB bf16 [b,n,c]
    short* WqT = (short*)(ws + 16 * MB);
    short* WkT = (short*)(ws + 16 * MB + 512 * 1024);
    short* WvT = (short*)(ws + 17 * MB);
    short* WoT = (short*)(ws + 17 * MB + 512 * 1024);
    short* Qsb = (short*)(ws + 18 * MB);     // 16 MB [b,h,q,hd]
    short* Kb  = (short*)(ws + 34 * MB);     // 16 MB [b,h,k,hd]
    short* Vt  = (short*)(ws + 50 * MB);     // 16 MB [b,h,hd,k]
    short* Ah  = (short*)(ws + 66 * MB);     // 16 MB [b,tok,c]

    prep_all<<<dim3(2304), 256, 0, stream>>>(x, xt, Wq, Wk, Wv, Wo,
                                             WqT, WkT, WvT, WoT);
    qkv_mfma<<<dim3(1536), 256, 0, stream>>>(xt, WqT, bq, WkT, bk, WvT, bv,
                                             Qsb, Kb, Vt);
    attn_mfma<<<dim3(512), 512, 0, stream>>>(Qsb, Kb, Vt, Ah);
    proj_mfma<<<dim3(512), 256, 0, stream>>>(Ah, WoT, bo, out);
}

// Round 17
// 108.272 us; speedup vs baseline: 1.0073x; 1.0073x over previous
//
#include <hip/hip_runtime.h>
#include <hip/hip_bf16.h>
#include <math.h>

// Problem constants
constexpr int B_  = 16;
constexpr int C_  = 512;
constexpr int N_  = 1024;   // 32*32 tokens
constexpr int NH_ = 8;
constexpr int HD_ = 64;

// 1/sqrt(64) * log2(e): softmax computed in exp2 domain
#define QSCALE 0.18033688f

typedef __attribute__((ext_vector_type(8))) short short8;
typedef __attribute__((ext_vector_type(4))) short short4v;
typedef __attribute__((ext_vector_type(4))) float f32x4;
#define MFMA16(a, b, c) __builtin_amdgcn_mfma_f32_16x16x32_bf16((a), (b), (c), 0, 0, 0)

#if __has_builtin(__builtin_amdgcn_exp2f)
#define EXP2(x) __builtin_amdgcn_exp2f(x)
#else
#define EXP2(x) exp2f(x)
#endif

__device__ __forceinline__ short f2bf(float f) {          // manual RNE (prep kernels)
    union { float f; unsigned u; } a; a.f = f;
    unsigned r = a.u + 0x7fffu + ((a.u >> 16) & 1u);
    return (short)(r >> 16);
}
__device__ __forceinline__ short f2bf_hw(float f) {       // hardware cvt (hot paths)
    __hip_bfloat16 h = __float2bfloat16(f);
    return *reinterpret_cast<short*>(&h);
}

// async global->LDS, 16B per lane; LDS dest = wave-uniform base + lane*16
__device__ __forceinline__ void gload_lds16(const void* g, void* l) {
    __builtin_amdgcn_global_load_lds(
        (const __attribute__((address_space(1))) unsigned*)g,
        (__attribute__((address_space(3))) unsigned*)l, 16, 0, 0);
}

// ---------------------------------------------------------------------------
// prep_all v2: vectorized transpose+cast (float4 loads, short8 stores).
//   wgid < 2048 : x[b][c][n] f32 -> xt[b][n][c] bf16 (64x64 tiles via LDS)
//   wgid >= 2048: W[c][co] f32 -> WT[co][c] bf16, 4 matrices
// ---------------------------------------------------------------------------
__global__ __launch_bounds__(256) void prep_all(
    const float* __restrict__ x, short* __restrict__ xt,
    const float* __restrict__ Wq, const float* __restrict__ Wk,
    const float* __restrict__ Wv, const float* __restrict__ Wo,
    short* __restrict__ WqT, short* __restrict__ WkT,
    short* __restrict__ WvT, short* __restrict__ WoT) {
    __shared__ float t[64][65];
    const int tid = threadIdx.x;
    const int wgid = blockIdx.x;

    const float* src;  short* dst;
    size_t srow0, scol0, drow0, dcol0;
    if (wgid < 2048) {
        const int xcd = wgid & 7;
        const int i = wgid >> 3;                 // 0..255
        const int b  = 2 * xcd + (i >= 128);
        const int tile = i & 127;
        const int tn = tile >> 3;
        const int tc = tile & 7;
        src = x;  dst = xt;
        srow0 = (size_t)b * C_ + tc * 64;  scol0 = (size_t)tn * 64;
        drow0 = (size_t)b * N_ + tn * 64;  dcol0 = (size_t)tc * 64;
        #pragma unroll
        for (int k = 0; k < 4; ++k) {
            int s = k * 256 + tid;
            int r = s >> 4, c4 = s & 15;
            float4 v = *(const float4*)&src[(srow0 + r) * N_ + scol0 + c4 * 4];
            *(float4*)&t[r][c4 * 4] = v;
        }
        __syncthreads();
        #pragma unroll
        for (int k = 0; k < 2; ++k) {
            int s = k * 256 + tid;
            int r2 = s >> 3, c8 = s & 7;
            short8 pk;
            #pragma unroll
            for (int j = 0; j < 8; ++j) pk[j] = f2bf(t[c8 * 8 + j][r2]);
            *(short8*)&dst[(drow0 + r2) * C_ + dcol0 + c8 * 8] = pk;
        }
    } else {
        const int idx0 = wgid - 2048;            // 0..255
        const int z = idx0 >> 6;
        src = (z == 0) ? Wq : (z == 1) ? Wk : (z == 2) ? Wv : Wo;
        dst = (z == 0) ? WqT : (z == 1) ? WkT : (z == 2) ? WvT : WoT;
        const int tile = idx0 & 63;
        const int tco = tile >> 3;
        const int tc  = tile & 7;
        srow0 = (size_t)tc * 64;   scol0 = (size_t)tco * 64;
        drow0 = (size_t)tco * 64;  dcol0 = (size_t)tc * 64;
        #pragma unroll
        for (int k = 0; k < 4; ++k) {
            int s = k * 256 + tid;
            int r = s >> 4, c4 = s & 15;
            float4 v = *(const float4*)&src[(srow0 + r) * C_ + scol0 + c4 * 4];
            *(float4*)&t[r][c4 * 4] = v;
        }
        __syncthreads();
        #pragma unroll
        for (int k = 0; k < 2; ++k) {
            int s = k * 256 + tid;
            int r2 = s >> 3, c8 = s & 7;
            short8 pk;
            #pragma unroll
            for (int j = 0; j < 8; ++j) pk[j] = f2bf(t[c8 * 8 + j][r2]);
            *(short8*)&dst[(drow0 + r2) * C_ + dcol0 + c8 * 8] = pk;
        }
    }
}

// ===========================================================================
// m97-style GEMM core macros (shared by qkv_mfma and proj_mfma):
// 128x128 tile, BK=64, 2x2 waves of 64x64. Double-buffered LDS staged via
// global_load_lds width=16, pre-swizzled global source (slot ^ (row&7)) with
// linear LDS dest; ds_read applies the same XOR -> conflict-free b128.
// smem layout: short smem[2][2][128][64] = 64 KB.
// ===========================================================================
#define GEMM_STAGE(buf, t)                                                    \
    {                                                                         \
        _Pragma("unroll")                                                     \
        for (int ii = 0; ii < 4; ++ii) {                                      \
            gload_lds16(Ag + arowoff + (size_t)ii * 8 * C_ + (t) * 64,        \
                        &smem[buf][0][wave * 32 + ii * 8][0]);                \
            gload_lds16(Bg + arowoff + (size_t)ii * 8 * C_ + (t) * 64,        \
                        &smem[buf][1][wave * 32 + ii * 8][0]);                \
        }                                                                     \
    }

#define GEMM_CORE()                                                           \
    GEMM_STAGE(0, 0);                                                         \
    __syncthreads();                                                          \
    for (int t = 0; t < 8; ++t) {                                             \
        const int buf = t & 1;                                                \
        if (t < 7) GEMM_STAGE(buf ^ 1, t + 1);                                \
        __builtin_amdgcn_s_setprio(1);                                        \
        _Pragma("unroll")                                                     \
        for (int ks = 0; ks < 2; ++ks) {                                      \
            short8 af[4], bf[4];                                              \
            const int sw = ((ks * 4 + g) ^ (c & 7)) << 3;                     \
            _Pragma("unroll")                                                 \
            for (int fm = 0; fm < 4; ++fm)                                    \
                af[fm] = *(const short8*)&smem[buf][0][wm * 64 + fm * 16 + c][sw]; \
            _Pragma("unroll")                                                 \
            for (int fn = 0; fn < 4; ++fn)                                    \
                bf[fn] = *(const short8*)&smem[buf][1][wn * 64 + fn * 16 + c][sw]; \
            _Pragma("unroll")                                                 \
            for (int fm = 0; fm < 4; ++fm)                                    \
                _Pragma("unroll")                                             \
                for (int fn = 0; fn < 4; ++fn)                                \
                    acc[fm][fn] = MFMA16(af[fm], bf[fn], acc[fm][fn]);        \
        }                                                                     \
        __builtin_amdgcn_s_setprio(0);                                        \
        __syncthreads();                                                      \
    }

// ---------------------------------------------------------------------------
// qkv_mfma: Y = xf @ W + b. 1D grid 1536, XCD-consistent swizzle.
// z=0 -> Qs (scaled), z=1 -> Kb, both [b,h,tok,hd]; z=2 -> Vt [b,h,hd,key].
// ---------------------------------------------------------------------------
__global__ __launch_bounds__(256) void qkv_mfma(
    const short* __restrict__ xt,
    const short* __restrict__ WqT, const float* __restrict__ bq,
    const short* __restrict__ WkT, const float* __restrict__ bk,
    const short* __restrict__ WvT, const float* __restrict__ bv,
    short* __restrict__ Qs, short* __restrict__ Kb, short* __restrict__ Vt) {
    const int wgid = blockIdx.x;
    const int xcd = wgid & 7;
    const int i = wgid >> 3;                 // 0..191
    const int b = 2 * xcd + (i >= 96);
    const int rem = (i >= 96) ? i - 96 : i;  // 0..95
    const int z = rem >> 5;                  // 0..2
    const int tile = rem & 31;
    const int mt = tile >> 2;                // 0..7 token tile (128 wide)
    const int nt = tile & 3;                 // 0..3 cout tile (128 wide)
    const int tid = threadIdx.x;
    const int wave = tid >> 6, lane = tid & 63;
    const int g = lane >> 4, c = lane & 15;
    const int wm = wave >> 1, wn = wave & 1;

    const short* W    = (z == 0) ? WqT : (z == 1) ? WkT : WvT;
    const float* bias = (z == 0) ? bq  : (z == 1) ? bk  : bv;

    __shared__ __align__(16) short smem[2][2][128][64];

    const short* Ag = xt + (size_t)b * N_ * C_ + (size_t)mt * 128 * C_;
    const short* Bg = W + (size_t)nt * 128 * C_;

    const int lrow = lane >> 3, lslot = lane & 7;
    const size_t arowoff = (size_t)(wave * 32 + lrow) * C_ + ((lslot ^ lrow) << 3);

    f32x4 acc[4][4] = {};
    GEMM_CORE();

    const int tok0 = mt * 128 + wm * 64;
    const int co0  = nt * 128 + wn * 64;
    const int h = co0 >> 6;
    const size_t bh = (size_t)(b * NH_ + h);

    if (z < 2) {
        short* Y = (z == 0) ? Qs : Kb;
        const float sc = (z == 0) ? QSCALE : 1.f;
        #pragma unroll
        for (int fm = 0; fm < 4; ++fm)
            #pragma unroll
            for (int fn = 0; fn < 4; ++fn)
                #pragma unroll
                for (int r = 0; r < 4; ++r) {
                    int tok = tok0 + fm * 16 + 4 * g + r;
                    int hd  = fn * 16 + c;
                    float v = (acc[fm][fn][r] + bias[co0 + hd]) * sc;
                    Y[(bh * N_ + tok) * HD_ + hd] = f2bf_hw(v);
                }
    } else {
        // V transpose via per-wave LDS (aliases staging smem after final barrier)
        short (*t72)[72] = (short(*)[72])((short*)smem + wave * 32 * 72);
        #pragma unroll
        for (int p = 0; p < 2; ++p) {       // two 32-row passes (in-order DS per wave)
            #pragma unroll
            for (int fn2 = 0; fn2 < 2; ++fn2) {
                int fnn = 2 * p + fn2;
                #pragma unroll
                for (int fm = 0; fm < 4; ++fm) {
                    short4v pk;
                    #pragma unroll
                    for (int r = 0; r < 4; ++r)
                        pk[r] = f2bf_hw(acc[fm][fnn][r] + bias[co0 + fnn * 16 + c]);
                    *(short4v*)&t72[fn2 * 16 + c][fm * 16 + 4 * g] = pk;
                }
            }
            int row = lane >> 1, half2 = lane & 1;
            int hd = p * 32 + row;
            size_t base = (bh * HD_ + hd) * N_ + tok0 + half2 * 32;
            #pragma unroll
            for (int j = 0; j < 4; ++j)
                *(short8*)&Vt[base + j * 8] = *(const short8*)&t72[row][half2 * 32 + j * 8];
        }
    }
}

// ---------------------------------------------------------------------------
// attn_mfma: static-max softmax flash attention — proven R10/R12 structure:
// 8 waves x 32 q = 256 q per block, grid 512 = 2 blocks/CU, double-buffered
// KV staging via registers (2-deep prefetch; one barrier/iter), l via
// MFMA-with-ones, XOR-swizzled KV and P. (R16's gload_lds staging was
// 1-deep only and measured +1.6us — reg staging is the proven form.)
// ---------------------------------------------------------------------------
__global__ __launch_bounds__(512) void attn_mfma(
    const short* __restrict__ Qs, const short* __restrict__ Kb,
    const short* __restrict__ Vt, short* __restrict__ Ah) {
    const int wgid = blockIdx.x;
    const int swz  = (wgid & 7) * 64 + (wgid >> 3);    // 512 wgs, bijective
    const int b  = swz >> 5;                           // XCD x owns b={2x,2x+1}
    const int h  = (swz >> 2) & 7;
    const int qt = swz & 3;
    const int tid = threadIdx.x;
    const int wave = tid >> 6, lane = tid & 63;
    const int g = lane >> 4, c = lane & 15;
    const int q0 = qt * 256 + wave * 32;               // wave's 32 q rows
    const size_t bh = (size_t)(b * NH_ + h);

    const short* Qw  = Qs + (bh * N_ + q0) * HD_;
    const short* Kbb = Kb + bh * N_ * HD_;
    const short* Vtb = Vt + bh * HD_ * N_;

    __shared__ short KV[2][2][4096];     // [dbuf][K|V][64x64 bf16, xor-swizzled]
    __shared__ short Pl[8][32][64];      // per-wave P, 8B-slot xor-swizzled
    short (*P)[64] = Pl[wave];
    const int px = (c & 7) << 1;         // P-swizzle term (row & 7 == c & 7)

    // staging: 512 threads, each one 16B K-slot and one 16B V-slot
    const int srow = tid >> 3;           // 0..63
    const int sc16 = tid & 7;
    const int kdst = srow * 64 + 8 * (sc16 ^ (srow & 7));
    short8 gk, gv;

    #define STAGE_LOAD(key0)                                                   \
        do {                                                                   \
            gk = *(const short8*)&Kbb[(size_t)((key0) + srow) * HD_ + sc16 * 8]; \
            gv = *(const short8*)&Vtb[(size_t)srow * N_ + (key0) + sc16 * 8];    \
        } while (0)
    #define STAGE_WRITE(buf)                                                   \
        do {                                                                   \
            *(short8*)&KV[buf][0][kdst] = gk;                                  \
            *(short8*)&KV[buf][1][kdst] = gv;                                  \
        } while (0)

    short8 qf[2][2];
    #pragma unroll
    for (int f = 0; f < 2; ++f)
        #pragma unroll
        for (int k0 = 0; k0 < 2; ++k0)
            qf[f][k0] = *(const short8*)&Qw[(f * 16 + c) * HD_ + k0 * 32 + g * 8];

    // ones B-fragment (bf16 1.0) for the l-accumulating MFMA
    short8 ones8;
    #pragma unroll
    for (int j = 0; j < 8; ++j) ones8[j] = (short)0x3F80;

    f32x4 o[2][4] = {};
    f32x4 lacc[2] = {};                  // D[row=q][col] all-equal l partials

    STAGE_LOAD(0);
    STAGE_WRITE(0);
    STAGE_LOAD(64);
    __syncthreads();

    int cur = 0;
    for (int it = 0; it < 16; ++it) {
        if (it < 15) STAGE_WRITE(cur ^ 1);
        if (it < 14) STAGE_LOAD((it + 2) * 64);

        const short* Kl = &KV[cur][0][0];
        const short* Vl = &KV[cur][1][0];

        f32x4 s[2][4] = {};
        __builtin_amdgcn_s_setprio(1);
        #pragma unroll
        for (int m = 0; m < 4; ++m) {
            const int row = m * 16 + c;
            short8 ka = *(const short8*)&Kl[row * 64 + 8 * ((g)     ^ (row & 7))];
            short8 kb = *(const short8*)&Kl[row * 64 + 8 * ((4 + g) ^ (row & 7))];
            s[0][m] = MFMA16(ka, qf[0][0], s[0][m]);
            s[0][m] = MFMA16(kb, qf[0][1], s[0][m]);
            s[1][m] = MFMA16(ka, qf[1][0], s[1][m]);
            s[1][m] = MFMA16(kb, qf[1][1], s[1][m]);
        }
        __builtin_amdgcn_s_setprio(0);

        // static-max softmax: p = exp2(s); pack to swizzled P (no reductions)
        #pragma unroll
        for (int f = 0; f < 2; ++f) {
            #pragma unroll
            for (int m = 0; m < 4; ++m) {
                short4v pk;
                #pragma unroll
                for (int r = 0; r < 4; ++r) pk[r] = f2bf_hw(EXP2(s[f][m][r]));
                *(short4v*)&P[f * 16 + c][((4 * m + g) ^ px) * 4] = pk;
            }
        }

        short8 pa[2][2];
        #pragma unroll
        for (int f = 0; f < 2; ++f)
            #pragma unroll
            for (int k0 = 0; k0 < 2; ++k0)
                pa[f][k0] = *(const short8*)&P[f * 16 + c][((k0 * 8 + 2 * g) ^ px) * 4];
        __builtin_amdgcn_s_setprio(1);
        // l partials on the matrix pipe: D[q][*] += sum_k P[q][k]
        lacc[0] = MFMA16(pa[0][0], ones8, lacc[0]);
        lacc[0] = MFMA16(pa[0][1], ones8, lacc[0]);
        lacc[1] = MFMA16(pa[1][0], ones8, lacc[1]);
        lacc[1] = MFMA16(pa[1][1], ones8, lacc[1]);
        #pragma unroll
        for (int n = 0; n < 4; ++n) {
            const int row = n * 16 + c;
            short8 va = *(const short8*)&Vl[row * 64 + 8 * ((g)     ^ (row & 7))];
            short8 vb = *(const short8*)&Vl[row * 64 + 8 * ((4 + g) ^ (row & 7))];
            o[0][n] = MFMA16(pa[0][0], va, o[0][n]);
            o[0][n] = MFMA16(pa[0][1], vb, o[0][n]);
            o[1][n] = MFMA16(pa[1][0], va, o[1][n]);
            o[1][n] = MFMA16(pa[1][1], vb, o[1][n]);
        }
        __builtin_amdgcn_s_setprio(0);

        __syncthreads();
        cur ^= 1;
    }
    #undef STAGE_LOAD
    #undef STAGE_WRITE

    // epilogue: l is lane-local (lacc[f][r] = l of q-row 4g+r); divide, store
    #pragma unroll
    for (int f = 0; f < 2; ++f) {
        float li[4];
        #pragma unroll
        for (int r = 0; r < 4; ++r) li[r] = 1.f / lacc[f][r];
        #pragma unroll
        for (int n = 0; n < 4; ++n)
            #pragma unroll
            for (int r = 0; r < 4; ++r) {
                int tok = q0 + f * 16 + 4 * g + r;
                int cc  = h * 64 + n * 16 + c;
                Ah[((size_t)b * N_ + tok) * C_ + cc] = f2bf_hw(o[f][n][r] * li[r]);
            }
    }
}

// ---------------------------------------------------------------------------
// proj_mfma: out[b,co,n] = bo[co] + sum_k A[tok][k] Wo[k][co]. m97-style
// staged GEMM core, 128x128 tile. 1D grid 512, XCD-consistent swizzle.
// Epilogue transposes 64x64 wave tile via LDS -> coalesced f32 stores.
// ---------------------------------------------------------------------------
__global__ __launch_bounds__(256) void proj_mfma(
    const short* __restrict__ Ah, const short* __restrict__ WoT,
    const float* __restrict__ bo, float* __restrict__ out) {
    const int wgid = blockIdx.x;
    const int xcd = wgid & 7;
    const int i = wgid >> 3;                 // 0..63
    const int b = 2 * xcd + (i >= 32);
    const int tile = i & 31;
    const int mt = tile >> 2;                // 0..7
    const int nt = tile & 3;                 // 0..3
    const int tid = threadIdx.x;
    const int wave = tid >> 6, lane = tid & 63;
    const int g = lane >> 4, c = lane & 15;
    const int wm = wave >> 1, wn = wave & 1;

    __shared__ __align__(16) short smem[2][2][128][64];

    const short* Ag = Ah + (size_t)b * N_ * C_ + (size_t)mt * 128 * C_;
    const short* Bg = WoT + (size_t)nt * 128 * C_;

    const int lrow = lane >> 3, lslot = lane & 7;
    const size_t arowoff = (size_t)(wave * 32 + lrow) * C_ + ((lslot ^ lrow) << 3);

    f32x4 acc[4][4] = {};
    GEMM_CORE();

    const int tok0 = mt * 128 + wm * 64;
    const int co0  = nt * 128 + wn * 64;

    // transpose 64x64 wave tile via LDS (aliases staging smem), two passes
    float (*tf)[68] = (float(*)[68])((float*)smem + wave * 32 * 68);
    #pragma unroll
    for (int p = 0; p < 2; ++p) {
        #pragma unroll
        for (int fm = 0; fm < 4; ++fm)
            #pragma unroll
            for (int fn2 = 0; fn2 < 2; ++fn2) {
                float4 v = *(float4*)&acc[fm][2 * p + fn2];
                *(float4*)&tf[fn2 * 16 + c][fm * 16 + 4 * g] = v;
            }
        int row = lane >> 1, half = lane & 1;
        int co = co0 + p * 32 + row;
        float bias = bo[co];
        float* ob = out + ((size_t)b * C_ + co) * N_ + tok0 + half * 32;
        #pragma unroll
        for (int j = 0; j < 8; ++j) {
            float4 v = *(const float4*)&tf[row][half * 32 + j * 4];
            v.x += bias; v.y += bias; v.z += bias; v.w += bias;
            *(float4*)&ob[j * 4] = v;
        }
    }
}

// ---------------------------------------------------------------------------
extern "C" void kernel_launch(void* const* d_in, const int* in_sizes, int n_in,
                              void* d_out, int out_size, void* d_ws, size_t ws_size,
                              hipStream_t stream) {
    (void)in_sizes; (void)n_in; (void)out_size; (void)ws_size;
    const float* x  = (const float*)d_in[0];
    const float* Wq = (const float*)d_in[1];
    const float* bq = (const float*)d_in[2];
    const float* Wk = (const float*)d_in[3];
    const float* bk = (const float*)d_in[4];
    const float* Wv = (const float*)d_in[5];
    const float* bv = (const float*)d_in[6];
    const float* Wo = (const float*)d_in[7];
    const float* bo = (const float*)d_in[8];
    float* out = (float*)d_out;

    char* ws = (char*)d_ws;
    const size_t MB = 1024 * 1024;
    short* xt  = (short*)(ws + 0 * MB);      // 16 MB bf16 [b,n,c]
    short* WqT = (short*)(ws + 16 * MB);
    short* WkT = (short*)(ws + 16 * MB + 512 * 1024);
    short* WvT = (short*)(ws + 17 * MB);
    short* WoT = (short*)(ws + 17 * MB + 512 * 1024);
    short* Qsb = (short*)(ws + 18 * MB);     // 16 MB [b,h,q,hd]
    short* Kb  = (short*)(ws + 34 * MB);     // 16 MB [b,h,k,hd]
    short* Vt  = (short*)(ws + 50 * MB);     // 16 MB [b,h,hd,k]
    short* Ah  = (short*)(ws + 66 * MB);     // 16 MB [b,tok,c]

    prep_all<<<dim3(2304), 256, 0, stream>>>(x, xt, Wq, Wk, Wv, Wo,
                                             WqT, WkT, WvT, WoT);
    qkv_mfma<<<dim3(1536), 256, 0, stream>>>(xt, WqT, bq, WkT, bk, WvT, bv,
                                             Qsb, Kb, Vt);
    attn_mfma<<<dim3(512), 512, 0, stream>>>(Qsb, Kb, Vt, Ah);
    proj_mfma<<<dim3(512), 256, 0, stream>>>(Ah, WoT, bo, out);
}